// Round 11
// baseline (228.109 us; speedup 1.0000x reference)
//
#include <hip/hip_runtime.h>
#include <cstdint>
#include <cstddef>

#define GEPS 1e-6f
#define LOG2E 1.44269504088896f

using bf16x8 = __attribute__((ext_vector_type(8))) short;   // 8 bf16 = 4 VGPRs
using f32x4  = __attribute__((ext_vector_type(4))) float;   // MFMA C/D frag

__device__ inline ushort f2bf(float x) {
    union { float f; uint32_t u; } v; v.f = x;
    uint32_t r = (v.u + 0x7fffu + ((v.u >> 16) & 1u)) >> 16;  // RNE
    return (ushort)r;
}
__device__ inline float bf2f(ushort b) {
    union { float f; uint32_t u; } v; v.u = ((uint32_t)b) << 16;
    return v.f;
}

// async global->LDS, 16 bytes per lane. LDS dest = wave-uniform base + lane*16.
__device__ inline void gll16(const void* g, void* l) {
    __builtin_amdgcn_global_load_lds(
        (const __attribute__((address_space(1))) void*)g,
        (__attribute__((address_space(3))) void*)l, 16, 0, 0);
}

// ---------------------------------------------------------------------------
// Kernel 1: merged preprocessing (one launch). Bx DEDICATED (R8 lesson).
//   blocks 0..511     : im2col via LDS transpose (b, py, ci-half)
//   blocks 512..1279  : conv weights -> bf16, k TAP-MAJOR (k = tap*256+ci)
//   blocks 1280..1343 : wo -> bf16
//   blocks 1344..3391 : bias table -> fragment-ordered Bx, PRE-SCALED by
//                       log2(e) so attn's softmax uses fma+exp2 directly.
// ---------------------------------------------------------------------------
__global__ __launch_bounds__(256) void prep_k(
    const float* __restrict__ x,
    const float* __restrict__ wq, const float* __restrict__ wk,
    const float* __restrict__ wv, const float* __restrict__ wo,
    const float* __restrict__ btab,
    ushort* __restrict__ Ab, ushort* __restrict__ Wbuf,
    ushort* __restrict__ wo_bf, ushort* __restrict__ Bx)
{
    __shared__ __align__(16) ushort Xs[3 * 34 * 128];   // 25.5 KB (max use)
    int tid = threadIdx.x;
    int blk = blockIdx.x;

    if (blk < 512) {
        // ---- im2col ----
        int b = blk >> 6, py = (blk >> 1) & 31, half = blk & 1;
#pragma unroll
        for (int p = tid; p < 768; p += 256) {
            int yy = p >> 8;
            int q = p & 255;
            int col = (q >> 7) ? 33 : 0;
            int ci = q & 127;
            Xs[(yy * 34 + col) * 128 + ci] = 0;
        }
#pragma unroll
        for (int it = 0; it < 12; ++it) {
            int j = it * 256 + tid;
            int ci_l = j / 24;
            int o = (j - ci_l * 24) * 4;
            int yy = o >> 5, xx = o & 31;
            int row = py - 1 + yy;
            float4 v = make_float4(0.f, 0.f, 0.f, 0.f);
            if (row >= 0 && row < 32)
                v = *(const float4*)&x[((size_t)(b * 256 + half * 128 + ci_l)) * 1024 + row * 32 + xx];
            int base = (yy * 34 + xx + 1) * 128 + ci_l;
            Xs[base + 0 * 128] = f2bf(v.x);
            Xs[base + 1 * 128] = f2bf(v.y);
            Xs[base + 2 * 128] = f2bf(v.z);
            Xs[base + 3 * 128] = f2bf(v.w);
        }
        __syncthreads();
        ushort* dst = Ab + (size_t)(b * 1024 + py * 32) * 2304;
#pragma unroll
        for (int it = 0; it < 18; ++it) {
            int idx = it * 256 + tid;       // 0..4607
            int ci8l = idx & 15;
            int tp = (idx >> 4) % 9;
            int px = idx / 144;
            int kh = tp / 3, kw = tp - kh * 3;
            uint4 p = *(const uint4*)&Xs[(kh * 34 + px + kw) * 128 + ci8l * 8];
            *(uint4*)&dst[(size_t)(px * 288 + tp * 32 + half * 16 + ci8l) * 8] = p;
        }
        return;
    }
    if (blk < 1280) {
        // ---- conv weight pack (LDS transpose) ----
        int wrow = blk - 512;               // 0..767
        int proj = wrow >> 8, co = wrow & 255;
        const float* src = ((proj == 0) ? wq : ((proj == 1) ? wk : wv)) + (size_t)co * 2304;
#pragma unroll
        for (int j = 0; j < 9; ++j) {
            int idx = j * 256 + tid;
            Xs[idx] = f2bf(src[idx]);       // coalesced fp32 read
        }
        __syncthreads();
        ushort* dst = Wbuf + (size_t)wrow * 2304;
#pragma unroll
        for (int j = 0; j < 9; ++j)          // k = j*256+tid: tap=j, ci=tid
            dst[j * 256 + tid] = Xs[tid * 9 + j];   // coalesced store
        return;
    }
    if (blk < 1344) {
        // ---- wo pack ----
        int t = (blk - 1280) * 256 + tid;    // 0..16383, 4 elems each
        float4 v = *(const float4*)&wo[(size_t)t * 4];
        union { uint2 u; ushort s[4]; } o;
        o.s[0] = f2bf(v.x); o.s[1] = f2bf(v.y); o.s[2] = f2bf(v.z); o.s[3] = f2bf(v.w);
        *(uint2*)&wo_bf[(size_t)t * 4] = o.u;
        return;
    }
    // ---- Bx expansion (values pre-scaled by log2e) ----
    int g = (blk - 1344) * 4 + (tid >> 6);   // tile id 0..8191
    int l = tid & 63;
    int h = g >> 10, qt = (g >> 4) & 63, kt = g & 15;
    int quad = l >> 4, c = l & 15;
    union { uint4 v[2]; ushort s[16]; } o;
#pragma unroll
    for (int f = 0; f < 4; ++f)
#pragma unroll
        for (int r = 0; r < 4; ++r) {
            int qrow = qt * 16 + quad * 4 + r;
            int key = kt * 64 + f * 16 + c;
            int dy = (qrow >> 5) - (key >> 5) + 31;
            int dx = (qrow & 31) - (key & 31) + 31;
            o.s[f * 4 + r] = f2bf(btab[(dy * 63 + dx) * 8 + h] * LOG2E);
        }
    uint4* dst = (uint4*)(Bx + ((size_t)g * 64 + l) * 16);
    dst[0] = o.v[0];
    dst[1] = o.v[1];
}

// ---------------------------------------------------------------------------
// Kernel 2: conv bf16 GEMM  C[M,N] = A[M,K] * B[N,K]^T, 128x128 tile, BK=64,
//   split-K via blockIdx.z, bf16 PLAIN-STORE partials to Cpart + z*M*N.
// ---------------------------------------------------------------------------
__global__ __launch_bounds__(256, 3) void gemm_bt(
    const ushort* __restrict__ A, const ushort* __restrict__ B,
    int M, int N, int K,
    ushort* __restrict__ Cpart)
{
    __shared__ __align__(16) ushort As[128 * 64];
    __shared__ __align__(16) ushort Bs[128 * 64];
    int tid = threadIdx.x;
    int mbase = blockIdx.x * 128, nbase = blockIdx.y * 128;
    int kspan = K / gridDim.z;
    int k0 = blockIdx.z * kspan;
    int wave = tid >> 6, lane = tid & 63;
    int wm = wave & 1, wn = wave >> 1;
    int quad = lane >> 4, c = lane & 15;

    int row_s = tid >> 3;               // 0..31 staging row within chunk
    int cc8 = (tid & 7) ^ (row_s & 7);  // swizzled global column-block
    ushort* ldsA = As + wave * 512;     // wave-uniform dest base (+lane*16B)
    ushort* ldsB = Bs + wave * 512;

    f32x4 acc[4][4];
#pragma unroll
    for (int i = 0; i < 4; ++i)
#pragma unroll
        for (int j = 0; j < 4; ++j) acc[i][j] = (f32x4){0.f, 0.f, 0.f, 0.f};

    for (int kb = k0; kb < k0 + kspan; kb += 64) {
        __syncthreads();
#pragma unroll
        for (int R = 0; R < 4; ++R) {
            int row = R * 32 + row_s;
            gll16(A + (size_t)(mbase + row) * K + kb + cc8 * 8,
                  ldsA + R * 2048);
            gll16(B + (size_t)(nbase + row) * K + kb + cc8 * 8,
                  ldsB + R * 2048);
        }
        __syncthreads();
#pragma unroll
        for (int kq = 0; kq < 2; ++kq) {
            bf16x8 af[4], bfr[4];
            int sw = ((kq * 4 + quad) ^ (c & 7)) * 8;
#pragma unroll
            for (int i = 0; i < 4; ++i) {
                af[i]  = *(const bf16x8*)&As[(wm * 64 + i * 16 + c) * 64 + sw];
                bfr[i] = *(const bf16x8*)&Bs[(wn * 64 + i * 16 + c) * 64 + sw];
            }
#pragma unroll
            for (int i = 0; i < 4; ++i)
#pragma unroll
                for (int j = 0; j < 4; ++j)
                    acc[i][j] = __builtin_amdgcn_mfma_f32_16x16x32_bf16(
                        af[i], bfr[j], acc[i][j], 0, 0, 0);
        }
    }

    ushort* Cp = Cpart + (size_t)blockIdx.z * M * N;
#pragma unroll
    for (int i = 0; i < 4; ++i) {
        int mrow = mbase + wm * 64 + i * 16 + quad * 4;
#pragma unroll
        for (int j = 0; j < 4; ++j) {
            int ncol = nbase + wn * 64 + j * 16 + c;
#pragma unroll
            for (int r = 0; r < 4; ++r)
                Cp[(size_t)(mrow + r) * N + ncol] = f2bf(acc[i][j][r]);
        }
    }
}

// ---------------------------------------------------------------------------
// Kernel 3: stats stage 1 — atomic-free partials over bf16 P0+P1.
// ---------------------------------------------------------------------------
__global__ __launch_bounds__(256) void stats1_k(const ushort* __restrict__ P0,
                                                const ushort* __restrict__ P1,
                                                float2* __restrict__ part)
{
    int t = blockIdx.x * 256 + threadIdx.x;     // 786432 threads x 8 elems
    size_t base = (size_t)t * 8;
    union { uint4 v; ushort s[8]; } a, b2;
    a.v  = *(const uint4*)&P0[base];
    b2.v = *(const uint4*)&P1[base];
    float s1 = 0.f, s2 = 0.f;
#pragma unroll
    for (int e = 0; e < 8; ++e) {
        float v = bf2f(a.s[e]) + bf2f(b2.s[e]);
        s1 += v; s2 += v * v;
    }
#pragma unroll
    for (int mk = 1; mk < 32; mk <<= 1) {
        s1 += __shfl_xor(s1, mk, 64);
        s2 += __shfl_xor(s2, mk, 64);
    }
    if ((threadIdx.x & 31) == 0) {
        int gg = t >> 5;                // group = one 256-elem (proj,m) segment
        int m = gg / 3;
        int proj = gg - m * 3;
        int b = m >> 10, slot = m & 1023;
        part[(proj * 8 + b) * 1024 + slot] = make_float2(s1, s2);
    }
}

// ---------------------------------------------------------------------------
// Kernel 3b: stats stage 2 — 48 blocks, each reduces 1024 float2 partials.
// ---------------------------------------------------------------------------
__global__ __launch_bounds__(256) void stats2_k(const float2* __restrict__ part,
                                                float* __restrict__ stats)
{
    __shared__ float w1[4], w2[4];
    int s = blockIdx.x, tid = threadIdx.x;
    float s1 = 0.f, s2 = 0.f;
#pragma unroll
    for (int i = 0; i < 4; ++i) {
        float2 v = part[(size_t)s * 1024 + tid * 4 + i];
        s1 += v.x; s2 += v.y;
    }
#pragma unroll
    for (int mk = 1; mk < 64; mk <<= 1) {
        s1 += __shfl_xor(s1, mk, 64);
        s2 += __shfl_xor(s2, mk, 64);
    }
    if ((tid & 63) == 0) { w1[tid >> 6] = s1; w2[tid >> 6] = s2; }
    __syncthreads();
    if (tid == 0) {
        stats[s * 2 + 0] = w1[0] + w1[1] + w1[2] + w1[3];
        stats[s * 2 + 1] = w2[0] + w2[1] + w2[2] + w2[3];
    }
}

// ---------------------------------------------------------------------------
// Kernel 4: GroupNorm(1) + exact GELU + head reshape; sums bf16 split-K
//   partials. q/k -> [b][h][n][d]; V -> fragment order Vx.
// ---------------------------------------------------------------------------
__global__ void gn_k(const ushort* __restrict__ P0, const ushort* __restrict__ P1,
                     const float* __restrict__ stats,
                     const float* __restrict__ gq, const float* __restrict__ bq,
                     const float* __restrict__ gk, const float* __restrict__ bk,
                     const float* __restrict__ gv, const float* __restrict__ bv,
                     ushort* __restrict__ qb, ushort* __restrict__ kb2,
                     ushort* __restrict__ vx)
{
    int t = blockIdx.x * 256 + threadIdx.x;     // 8192 * 96 threads
    int m = t / 96;
    int nn = (t - m * 96) * 8;
    int proj = nn >> 8, co = nn & 255;
    int b = m >> 10, px = m & 1023;
    float s1 = stats[(proj * 8 + b) * 2 + 0];
    float s2 = stats[(proj * 8 + b) * 2 + 1];
    const float Ninv = 1.f / 262144.f;
    float mu = s1 * Ninv;
    float var = fmaxf(s2 * Ninv - mu * mu, 0.f);
    float rsig = rsqrtf(var + GEPS);
    const float* gam = (proj == 0) ? gq : ((proj == 1) ? gk : gv);
    const float* bet = (proj == 0) ? bq : ((proj == 1) ? bk : bv);

    size_t base = (size_t)m * 768 + nn;
    union { uint4 v; ushort s[8]; } a, c2;
    a.v  = *(const uint4*)&P0[base];
    c2.v = *(const uint4*)&P1[base];
    union { uint4 v; ushort s[8]; } outp;
#pragma unroll
    for (int e = 0; e < 8; ++e) {
        int cc = co + e;
        float xv = bf2f(a.s[e]) + bf2f(c2.s[e]);
        float xn = (xv - mu) * rsig * gam[cc] + bet[cc];
        float ge = 0.5f * xn * (1.f + erff(xn * 0.70710678118654752f));
        outp.s[e] = f2bf(ge);
    }
    int h = co >> 5, d = co & 31;
    if (proj == 0) {
        *(uint4*)(qb + ((((size_t)b * 8 + h) * 1024 + px) * 32 + d)) = outp.v;
    } else if (proj == 1) {
        *(uint4*)(kb2 + ((((size_t)b * 8 + h) * 1024 + px) * 32 + d)) = outp.v;
    } else {
        // Vx[bh][kca=px>>5][half=d>>4][lane=quad*16+(d&15)][j=px&7]
        ushort* vb = vx + ((size_t)b * 8 + h) * 32768;
        int kca = px >> 5, quad = (px >> 3) & 3, j = px & 7;
#pragma unroll
        for (int e = 0; e < 8; ++e) {
            int dd = d + e;
            vb[(((kca * 2 + (dd >> 4)) * 64) + quad * 16 + (dd & 15)) * 8 + j] = outp.s[e];
        }
    }
}

// ---------------------------------------------------------------------------
// Kernel 5: fused attention, KEY-SPLIT z=2 (2048 blocks -> ~8 blocks/CU).
//   Softmax via exp2(S*log2e + bias') — Bx is pre-scaled, saving one VALU
//   op per score. Writes UNNORMALIZED bf16 O partials + fp32 l partials.
// ---------------------------------------------------------------------------
__global__ __launch_bounds__(256, 8) void attn_k(
    const ushort* __restrict__ qb, const ushort* __restrict__ kb,
    const ushort* __restrict__ vx, const ushort* __restrict__ Bx,
    ushort* __restrict__ Opart, float* __restrict__ lpart)
{
    __shared__ __align__(16) ushort Pl[4 * 16 * 72];
    int tid = threadIdx.x, wave = tid >> 6, lane = tid & 63;
    int quad = lane >> 4, c = lane & 15;
    int bh = blockIdx.y;               // b*8 + h
    int h = bh & 7;
    int z = blockIdx.z;
    int qbase = blockIdx.x * 64 + wave * 16;

    const ushort* Q  = qb + (size_t)bh * 1024 * 32;
    const ushort* Kp = kb + (size_t)bh * 1024 * 32;
    const ushort* Vb = vx + (size_t)bh * 32768;
    const ushort* bxp = Bx + (((size_t)(h * 64 + (qbase >> 4)) * 16) * 64 + lane) * 16;
    ushort* Pw = Pl + wave * 16 * 72;

    bf16x8 qf = *(const bf16x8*)&Q[(qbase + c) * 32 + quad * 8];

    float l_[4] = {0.f, 0.f, 0.f, 0.f};
    f32x4 Of0 = {0.f, 0.f, 0.f, 0.f}, Of1 = {0.f, 0.f, 0.f, 0.f};

    for (int kb64 = z * 512; kb64 < z * 512 + 512; kb64 += 64) {
        f32x4 S[4];
        f32x4 zf = {0.f, 0.f, 0.f, 0.f};
#pragma unroll
        for (int f = 0; f < 4; ++f) {
            bf16x8 kf = *(const bf16x8*)&Kp[(kb64 + f * 16 + c) * 32 + quad * 8];
            S[f] = __builtin_amdgcn_mfma_f32_16x16x32_bf16(qf, kf, zf, 0, 0, 0);
        }
        // fragment-ordered pre-scaled bias: 32 B per lane, coalesced
        union { uint4 v[2]; ushort s[16]; } bu;
        const uint4* bsrc = (const uint4*)(bxp + (size_t)(kb64 >> 6) * 1024);
        bu.v[0] = bsrc[0];
        bu.v[1] = bsrc[1];
#pragma unroll
        for (int f = 0; f < 4; ++f)
#pragma unroll
            for (int r = 0; r < 4; ++r) {
                float p = __builtin_amdgcn_exp2f(
                    fmaf(S[f][r], LOG2E, bf2f(bu.s[f * 4 + r])));
                S[f][r] = p;
                l_[r] += p;
            }
        // P (C-layout) -> LDS -> A-layout; per-wave slice, no barrier needed
#pragma unroll
        for (int f = 0; f < 4; ++f)
#pragma unroll
            for (int r = 0; r < 4; ++r)
                Pw[(quad * 4 + r) * 72 + f * 16 + c] = f2bf(S[f][r]);
#pragma unroll
        for (int kc = 0; kc < 2; ++kc) {
            int kca = (kb64 >> 5) + kc;
            bf16x8 pf = *(const bf16x8*)&Pw[c * 72 + kc * 32 + quad * 8];
            bf16x8 vf0 = *(const bf16x8*)&Vb[((kca * 2 + 0) * 64 + lane) * 8];
            Of0 = __builtin_amdgcn_mfma_f32_16x16x32_bf16(pf, vf0, Of0, 0, 0, 0);
            bf16x8 vf1 = *(const bf16x8*)&Vb[((kca * 2 + 1) * 64 + lane) * 8];
            Of1 = __builtin_amdgcn_mfma_f32_16x16x32_bf16(pf, vf1, Of1, 0, 0, 0);
        }
    }
#pragma unroll
    for (int r = 0; r < 4; ++r) {
        float l = l_[r];
        l += __shfl_xor(l, 1, 64);
        l += __shfl_xor(l, 2, 64);
        l += __shfl_xor(l, 4, 64);
        l += __shfl_xor(l, 8, 64);
        int qr = qbase + quad * 4 + r;
        size_t ob = (((size_t)z * 64 + bh) * 1024 + qr) * 32;
        Opart[ob + c]      = f2bf(Of0[r]);
        Opart[ob + 16 + c] = f2bf(Of1[r]);
        if (c == 0) lpart[(size_t)z * 65536 + bh * 1024 + qr] = l;
    }
}

// ---------------------------------------------------------------------------
// Kernel 6: out-projection GEMM with FUSED key-split combine.
//   C[o=256][n=8192] = wo[o][c] * attn[n][c]^T, 128x128 tile, BK=64,
//   grid (2,64). A (wo_bf) staged via global_load_lds with the XOR swizzle;
//   B staged MANUALLY: load O0/O1 bf16 partials + l partials, normalize
//   (O0+O1)/(l0+l1), ds_write with the SAME LDS addressing gll16 produces —
//   fragment-read path is byte-identical to gemm_bt's. Removes combine_k
//   and the attnout round-trip. Epilogue: d_out[b][o][px] = C + bias[o].
// ---------------------------------------------------------------------------
__global__ __launch_bounds__(256, 3) void oproj_k(
    const ushort* __restrict__ Awo, const ushort* __restrict__ Opart,
    const float* __restrict__ lpart,
    float* __restrict__ Cout, const float* __restrict__ bias)
{
    __shared__ __align__(16) ushort As[128 * 64];
    __shared__ __align__(16) ushort Bs[128 * 64];
    int tid = threadIdx.x;
    int mbase = blockIdx.x * 128, nbase = blockIdx.y * 128;
    int wave = tid >> 6, lane = tid & 63;
    int wm = wave & 1, wn = wave >> 1;
    int quad = lane >> 4, c = lane & 15;

    int row_s = tid >> 3;               // 0..31 staging row within chunk
    int cc8 = (tid & 7) ^ (row_s & 7);  // swizzled global column-block
    ushort* ldsA = As + wave * 512;

    f32x4 acc[4][4];
#pragma unroll
    for (int i = 0; i < 4; ++i)
#pragma unroll
        for (int j = 0; j < 4; ++j) acc[i][j] = (f32x4){0.f, 0.f, 0.f, 0.f};

    for (int kb = 0; kb < 256; kb += 64) {
        __syncthreads();
#pragma unroll
        for (int R = 0; R < 4; ++R) {
            int row = R * 32 + row_s;
            gll16(Awo + (size_t)(mbase + row) * 256 + kb + cc8 * 8,
                  ldsA + R * 2048);
            // ---- manual B staging with fused combine ----
            int n = nbase + row;            // output pixel index b*1024+qr
            int qr = n & 1023, bb = n >> 10;
            int cb = (kb >> 3) + cc8;       // global channel-block 0..31
            int hh = cb >> 2, d0 = (cb & 3) * 8;
            int qg = (bb * 8 + hh) * 1024 + qr;
            union { uint4 v; ushort s[8]; } o0, o1;
            o0.v = *(const uint4*)&Opart[(size_t)qg * 32 + d0];
            o1.v = *(const uint4*)&Opart[2097152 + (size_t)qg * 32 + d0];
            float inv = 1.f / (lpart[qg] + lpart[65536 + qg]);
            union { uint4 v; ushort s[8]; } ob;
#pragma unroll
            for (int e = 0; e < 8; ++e)
                ob.s[e] = f2bf((bf2f(o0.s[e]) + bf2f(o1.s[e])) * inv);
            *(uint4*)&Bs[row * 64 + (tid & 7) * 8] = ob.v;
        }
        __syncthreads();
#pragma unroll
        for (int kq = 0; kq < 2; ++kq) {
            bf16x8 af[4], bfr[4];
            int sw = ((kq * 4 + quad) ^ (c & 7)) * 8;
#pragma unroll
            for (int i = 0; i < 4; ++i) {
                af[i]  = *(const bf16x8*)&As[(wm * 64 + i * 16 + c) * 64 + sw];
                bfr[i] = *(const bf16x8*)&Bs[(wn * 64 + i * 16 + c) * 64 + sw];
            }
#pragma unroll
            for (int i = 0; i < 4; ++i)
#pragma unroll
                for (int j = 0; j < 4; ++j)
                    acc[i][j] = __builtin_amdgcn_mfma_f32_16x16x32_bf16(
                        af[i], bfr[j], acc[i][j], 0, 0, 0);
        }
    }

#pragma unroll
    for (int i = 0; i < 4; ++i) {
        int mrow0 = mbase + wm * 64 + i * 16 + quad * 4;
#pragma unroll
        for (int j = 0; j < 4; ++j) {
            int ncol = nbase + wn * 64 + j * 16 + c;
            int bb = ncol >> 10, px = ncol & 1023;
#pragma unroll
            for (int r = 0; r < 4; ++r) {
                int o = mrow0 + r;
                Cout[((size_t)bb * 256 + o) * 1024 + px] = acc[i][j][r] + bias[o];
            }
        }
    }
}

// ---------------------------------------------------------------------------
extern "C" void kernel_launch(void* const* d_in, const int* in_sizes, int n_in,
                              void* d_out, int out_size, void* d_ws, size_t ws_size,
                              hipStream_t stream)
{
    const float* x    = (const float*)d_in[0];
    const float* wq   = (const float*)d_in[1];
    const float* wk   = (const float*)d_in[2];
    const float* wv   = (const float*)d_in[3];
    const float* gq   = (const float*)d_in[4];
    const float* bq   = (const float*)d_in[5];
    const float* gk   = (const float*)d_in[6];
    const float* bk   = (const float*)d_in[7];
    const float* gv   = (const float*)d_in[8];
    const float* bv   = (const float*)d_in[9];
    const float* btab = (const float*)d_in[10];
    const float* wo   = (const float*)d_in[11];
    const float* bo   = (const float*)d_in[12];
    float* out = (float*)d_out;

    char* w = (char*)d_ws;
    size_t off = 0;
    auto alloc = [&](size_t bytes) -> char* {
        char* p = w + off;
        off += (bytes + 255) & ~(size_t)255;
        return p;
    };
    ushort* Abuf    = (ushort*)alloc(8192ull * 2304 * 2);   // im2col patches (36.9 MB)
    ushort* Wbuf    = (ushort*)alloc(768ull * 2304 * 2);    // concat conv weights
    ushort* wo_bf   = (ushort*)alloc(65536ull * 2);         // out-proj weight
    ushort* Bx      = (ushort*)alloc(8192ull * 64 * 16 * 2);// bias frags (16.7 MB, DEDICATED)
    ushort* P0      = (ushort*)alloc(8192ull * 768 * 2);    // split-K partial 0 (bf16)
    ushort* P1      = (ushort*)alloc(8192ull * 768 * 2);    // split-K partial 1 (bf16)
    float2* part    = (float2*)alloc(48ull * 1024 * 8);     // stats partials
    float*  stats   = (float*)alloc(384);                   // [proj][b][sum,sumsq]
    ushort* Opart   = (ushort*)alloc(2ull * 64 * 1024 * 32 * 2);  // attn O partials (bf16)
    float*  lpart   = (float*)alloc(2ull * 64 * 1024 * 4);        // attn l partials
    // aliases into Abuf (dead after the conv GEMM; stream-ordered):
    ushort* qb      = (ushort*)Abuf;                        // 4 MB
    ushort* kb2     = qb  + 8ull * 8 * 1024 * 32;           // 4 MB
    ushort* vx      = kb2 + 8ull * 8 * 1024 * 32;           // 4 MB (fragment order)

    prep_k<<<3392, 256, 0, stream>>>(x, wq, wk, wv, wo, btab,
                                     Abuf, Wbuf, wo_bf, Bx);
    gemm_bt<<<dim3(64, 6, 2), 256, 0, stream>>>(Abuf, Wbuf, 8192, 768, 2304, P0);
    stats1_k<<<3072, 256, 0, stream>>>(P0, P1, part);
    stats2_k<<<48, 256, 0, stream>>>(part, stats);
    gn_k<<<3072, 256, 0, stream>>>(P0, P1, stats, gq, bq, gk, bk, gv, bv,
                                   qb, kb2, vx);
    attn_k<<<dim3(16, 64, 2), 256, 0, stream>>>(qb, kb2, vx, Bx, Opart, lpart);
    oproj_k<<<dim3(2, 64), 256, 0, stream>>>(wo_bf, Opart, lpart, out, bo);
}

// Round 12
// 223.640 us; speedup vs baseline: 1.0200x; 1.0200x over previous
//
#include <hip/hip_runtime.h>
#include <cstdint>
#include <cstddef>

#define GEPS 1e-6f
#define LOG2E 1.44269504088896f

using bf16x8 = __attribute__((ext_vector_type(8))) short;   // 8 bf16 = 4 VGPRs
using f32x4  = __attribute__((ext_vector_type(4))) float;   // MFMA C/D frag

__device__ inline ushort f2bf(float x) {
    union { float f; uint32_t u; } v; v.f = x;
    uint32_t r = (v.u + 0x7fffu + ((v.u >> 16) & 1u)) >> 16;  // RNE
    return (ushort)r;
}
__device__ inline float bf2f(ushort b) {
    union { float f; uint32_t u; } v; v.u = ((uint32_t)b) << 16;
    return v.f;
}

// async global->LDS, 16 bytes per lane. LDS dest = wave-uniform base + lane*16.
__device__ inline void gll16(const void* g, void* l) {
    __builtin_amdgcn_global_load_lds(
        (const __attribute__((address_space(1))) void*)g,
        (__attribute__((address_space(3))) void*)l, 16, 0, 0);
}

// ---------------------------------------------------------------------------
// Kernel 1: merged preprocessing (one launch). Bx DEDICATED (R8 lesson).
//   blocks 0..511     : im2col via LDS transpose (b, py, ci-half)
//   blocks 512..1279  : conv weights -> bf16, k TAP-MAJOR (k = tap*256+ci)
//   blocks 1280..1343 : wo -> bf16
//   blocks 1344..3391 : bias table -> fragment-ordered Bx, PRE-SCALED by
//                       log2(e) so attn's softmax is exp2(fma(S,log2e,b)).
// ---------------------------------------------------------------------------
__global__ __launch_bounds__(256) void prep_k(
    const float* __restrict__ x,
    const float* __restrict__ wq, const float* __restrict__ wk,
    const float* __restrict__ wv, const float* __restrict__ wo,
    const float* __restrict__ btab,
    ushort* __restrict__ Ab, ushort* __restrict__ Wbuf,
    ushort* __restrict__ wo_bf, ushort* __restrict__ Bx)
{
    __shared__ __align__(16) ushort Xs[3 * 34 * 128];   // 25.5 KB (max use)
    int tid = threadIdx.x;
    int blk = blockIdx.x;

    if (blk < 512) {
        // ---- im2col ----
        int b = blk >> 6, py = (blk >> 1) & 31, half = blk & 1;
#pragma unroll
        for (int p = tid; p < 768; p += 256) {
            int yy = p >> 8;
            int q = p & 255;
            int col = (q >> 7) ? 33 : 0;
            int ci = q & 127;
            Xs[(yy * 34 + col) * 128 + ci] = 0;
        }
#pragma unroll
        for (int it = 0; it < 12; ++it) {
            int j = it * 256 + tid;
            int ci_l = j / 24;
            int o = (j - ci_l * 24) * 4;
            int yy = o >> 5, xx = o & 31;
            int row = py - 1 + yy;
            float4 v = make_float4(0.f, 0.f, 0.f, 0.f);
            if (row >= 0 && row < 32)
                v = *(const float4*)&x[((size_t)(b * 256 + half * 128 + ci_l)) * 1024 + row * 32 + xx];
            int base = (yy * 34 + xx + 1) * 128 + ci_l;
            Xs[base + 0 * 128] = f2bf(v.x);
            Xs[base + 1 * 128] = f2bf(v.y);
            Xs[base + 2 * 128] = f2bf(v.z);
            Xs[base + 3 * 128] = f2bf(v.w);
        }
        __syncthreads();
        ushort* dst = Ab + (size_t)(b * 1024 + py * 32) * 2304;
#pragma unroll
        for (int it = 0; it < 18; ++it) {
            int idx = it * 256 + tid;       // 0..4607
            int ci8l = idx & 15;
            int tp = (idx >> 4) % 9;
            int px = idx / 144;
            int kh = tp / 3, kw = tp - kh * 3;
            uint4 p = *(const uint4*)&Xs[(kh * 34 + px + kw) * 128 + ci8l * 8];
            *(uint4*)&dst[(size_t)(px * 288 + tp * 32 + half * 16 + ci8l) * 8] = p;
        }
        return;
    }
    if (blk < 1280) {
        // ---- conv weight pack (LDS transpose) ----
        int wrow = blk - 512;               // 0..767
        int proj = wrow >> 8, co = wrow & 255;
        const float* src = ((proj == 0) ? wq : ((proj == 1) ? wk : wv)) + (size_t)co * 2304;
#pragma unroll
        for (int j = 0; j < 9; ++j) {
            int idx = j * 256 + tid;
            Xs[idx] = f2bf(src[idx]);       // coalesced fp32 read
        }
        __syncthreads();
        ushort* dst = Wbuf + (size_t)wrow * 2304;
#pragma unroll
        for (int j = 0; j < 9; ++j)          // k = j*256+tid: tap=j, ci=tid
            dst[j * 256 + tid] = Xs[tid * 9 + j];   // coalesced store
        return;
    }
    if (blk < 1344) {
        // ---- wo pack ----
        int t = (blk - 1280) * 256 + tid;    // 0..16383, 4 elems each
        float4 v = *(const float4*)&wo[(size_t)t * 4];
        union { uint2 u; ushort s[4]; } o;
        o.s[0] = f2bf(v.x); o.s[1] = f2bf(v.y); o.s[2] = f2bf(v.z); o.s[3] = f2bf(v.w);
        *(uint2*)&wo_bf[(size_t)t * 4] = o.u;
        return;
    }
    // ---- Bx expansion (values pre-scaled by log2e) ----
    int g = (blk - 1344) * 4 + (tid >> 6);   // tile id 0..8191
    int l = tid & 63;
    int h = g >> 10, qt = (g >> 4) & 63, kt = g & 15;
    int quad = l >> 4, c = l & 15;
    union { uint4 v[2]; ushort s[16]; } o;
#pragma unroll
    for (int f = 0; f < 4; ++f)
#pragma unroll
        for (int r = 0; r < 4; ++r) {
            int qrow = qt * 16 + quad * 4 + r;
            int key = kt * 64 + f * 16 + c;
            int dy = (qrow >> 5) - (key >> 5) + 31;
            int dx = (qrow & 31) - (key & 31) + 31;
            o.s[f * 4 + r] = f2bf(btab[(dy * 63 + dx) * 8 + h] * LOG2E);
        }
    uint4* dst = (uint4*)(Bx + ((size_t)g * 64 + l) * 16);
    dst[0] = o.v[0];
    dst[1] = o.v[1];
}

// ---------------------------------------------------------------------------
// Kernel 2/8: bf16 GEMM  C[M,N] = A[M,K] * B[N,K]^T, 128x128 tile, BK=64,
//   split-K via blockIdx.z, PLAIN-STORE partials. (R10 structure — the R11
//   fused-combine oproj regressed: 128-block grid can't hide combine latency.)
//   mode 0 (conv): store BF16 partial to Cpart + z*M*N
//   mode 1 (out-proj, gridDim.z==1): store fp32 d_out[b][o][px] = C + bias[o]
// ---------------------------------------------------------------------------
__global__ __launch_bounds__(256, 3) void gemm_bt(
    const ushort* __restrict__ A, const ushort* __restrict__ B,
    int M, int N, int K,
    ushort* __restrict__ Cpart,
    float* __restrict__ Cout, const float* __restrict__ bias, int mode)
{
    __shared__ __align__(16) ushort As[128 * 64];
    __shared__ __align__(16) ushort Bs[128 * 64];
    int tid = threadIdx.x;
    int mbase = blockIdx.x * 128, nbase = blockIdx.y * 128;
    int kspan = K / gridDim.z;
    int k0 = blockIdx.z * kspan;
    int wave = tid >> 6, lane = tid & 63;
    int wm = wave & 1, wn = wave >> 1;
    int quad = lane >> 4, c = lane & 15;

    int row_s = tid >> 3;               // 0..31 staging row within chunk
    int cc8 = (tid & 7) ^ (row_s & 7);  // swizzled global column-block
    ushort* ldsA = As + wave * 512;     // wave-uniform dest base (+lane*16B)
    ushort* ldsB = Bs + wave * 512;

    f32x4 acc[4][4];
#pragma unroll
    for (int i = 0; i < 4; ++i)
#pragma unroll
        for (int j = 0; j < 4; ++j) acc[i][j] = (f32x4){0.f, 0.f, 0.f, 0.f};

    for (int kb = k0; kb < k0 + kspan; kb += 64) {
        __syncthreads();
#pragma unroll
        for (int R = 0; R < 4; ++R) {
            int row = R * 32 + row_s;
            gll16(A + (size_t)(mbase + row) * K + kb + cc8 * 8,
                  ldsA + R * 2048);
            gll16(B + (size_t)(nbase + row) * K + kb + cc8 * 8,
                  ldsB + R * 2048);
        }
        __syncthreads();
#pragma unroll
        for (int kq = 0; kq < 2; ++kq) {
            bf16x8 af[4], bfr[4];
            int sw = ((kq * 4 + quad) ^ (c & 7)) * 8;
#pragma unroll
            for (int i = 0; i < 4; ++i) {
                af[i]  = *(const bf16x8*)&As[(wm * 64 + i * 16 + c) * 64 + sw];
                bfr[i] = *(const bf16x8*)&Bs[(wn * 64 + i * 16 + c) * 64 + sw];
            }
#pragma unroll
            for (int i = 0; i < 4; ++i)
#pragma unroll
                for (int j = 0; j < 4; ++j)
                    acc[i][j] = __builtin_amdgcn_mfma_f32_16x16x32_bf16(
                        af[i], bfr[j], acc[i][j], 0, 0, 0);
        }
    }

    if (mode == 0) {
        ushort* Cp = Cpart + (size_t)blockIdx.z * M * N;
#pragma unroll
        for (int i = 0; i < 4; ++i) {
            int mrow = mbase + wm * 64 + i * 16 + quad * 4;
#pragma unroll
            for (int j = 0; j < 4; ++j) {
                int ncol = nbase + wn * 64 + j * 16 + c;
#pragma unroll
                for (int r = 0; r < 4; ++r)
                    Cp[(size_t)(mrow + r) * N + ncol] = f2bf(acc[i][j][r]);
            }
        }
    } else {
#pragma unroll
        for (int i = 0; i < 4; ++i) {
            int mrow0 = mbase + wm * 64 + i * 16 + quad * 4;
#pragma unroll
            for (int j = 0; j < 4; ++j) {
                int ncol = nbase + wn * 64 + j * 16 + c;
                int bb = ncol >> 10, px = ncol & 1023;
#pragma unroll
                for (int r = 0; r < 4; ++r) {
                    int o = mrow0 + r;
                    Cout[((size_t)bb * 256 + o) * 1024 + px] = acc[i][j][r] + bias[o];
                }
            }
        }
    }
}

// ---------------------------------------------------------------------------
// Kernel 3: stats stage 1 — atomic-free partials over bf16 P0+P1.
// ---------------------------------------------------------------------------
__global__ __launch_bounds__(256) void stats1_k(const ushort* __restrict__ P0,
                                                const ushort* __restrict__ P1,
                                                float2* __restrict__ part)
{
    int t = blockIdx.x * 256 + threadIdx.x;     // 786432 threads x 8 elems
    size_t base = (size_t)t * 8;
    union { uint4 v; ushort s[8]; } a, b2;
    a.v  = *(const uint4*)&P0[base];
    b2.v = *(const uint4*)&P1[base];
    float s1 = 0.f, s2 = 0.f;
#pragma unroll
    for (int e = 0; e < 8; ++e) {
        float v = bf2f(a.s[e]) + bf2f(b2.s[e]);
        s1 += v; s2 += v * v;
    }
#pragma unroll
    for (int mk = 1; mk < 32; mk <<= 1) {
        s1 += __shfl_xor(s1, mk, 64);
        s2 += __shfl_xor(s2, mk, 64);
    }
    if ((threadIdx.x & 31) == 0) {
        int gg = t >> 5;                // group = one 256-elem (proj,m) segment
        int m = gg / 3;
        int proj = gg - m * 3;
        int b = m >> 10, slot = m & 1023;
        part[(proj * 8 + b) * 1024 + slot] = make_float2(s1, s2);
    }
}

// ---------------------------------------------------------------------------
// Kernel 3b: stats stage 2 — 48 blocks, each reduces 1024 float2 partials.
// ---------------------------------------------------------------------------
__global__ __launch_bounds__(256) void stats2_k(const float2* __restrict__ part,
                                                float* __restrict__ stats)
{
    __shared__ float w1[4], w2[4];
    int s = blockIdx.x, tid = threadIdx.x;
    float s1 = 0.f, s2 = 0.f;
#pragma unroll
    for (int i = 0; i < 4; ++i) {
        float2 v = part[(size_t)s * 1024 + tid * 4 + i];
        s1 += v.x; s2 += v.y;
    }
#pragma unroll
    for (int mk = 1; mk < 64; mk <<= 1) {
        s1 += __shfl_xor(s1, mk, 64);
        s2 += __shfl_xor(s2, mk, 64);
    }
    if ((tid & 63) == 0) { w1[tid >> 6] = s1; w2[tid >> 6] = s2; }
    __syncthreads();
    if (tid == 0) {
        stats[s * 2 + 0] = w1[0] + w1[1] + w1[2] + w1[3];
        stats[s * 2 + 1] = w2[0] + w2[1] + w2[2] + w2[3];
    }
}

// ---------------------------------------------------------------------------
// Kernel 4: GroupNorm(1) + exact GELU + head reshape; sums bf16 split-K
//   partials. q/k -> [b][h][n][d]; V -> fragment order Vx.
// ---------------------------------------------------------------------------
__global__ void gn_k(const ushort* __restrict__ P0, const ushort* __restrict__ P1,
                     const float* __restrict__ stats,
                     const float* __restrict__ gq, const float* __restrict__ bq,
                     const float* __restrict__ gk, const float* __restrict__ bk,
                     const float* __restrict__ gv, const float* __restrict__ bv,
                     ushort* __restrict__ qb, ushort* __restrict__ kb2,
                     ushort* __restrict__ vx)
{
    int t = blockIdx.x * 256 + threadIdx.x;     // 8192 * 96 threads
    int m = t / 96;
    int nn = (t - m * 96) * 8;
    int proj = nn >> 8, co = nn & 255;
    int b = m >> 10, px = m & 1023;
    float s1 = stats[(proj * 8 + b) * 2 + 0];
    float s2 = stats[(proj * 8 + b) * 2 + 1];
    const float Ninv = 1.f / 262144.f;
    float mu = s1 * Ninv;
    float var = fmaxf(s2 * Ninv - mu * mu, 0.f);
    float rsig = rsqrtf(var + GEPS);
    const float* gam = (proj == 0) ? gq : ((proj == 1) ? gk : gv);
    const float* bet = (proj == 0) ? bq : ((proj == 1) ? bk : bv);

    size_t base = (size_t)m * 768 + nn;
    union { uint4 v; ushort s[8]; } a, c2;
    a.v  = *(const uint4*)&P0[base];
    c2.v = *(const uint4*)&P1[base];
    union { uint4 v; ushort s[8]; } outp;
#pragma unroll
    for (int e = 0; e < 8; ++e) {
        int cc = co + e;
        float xv = bf2f(a.s[e]) + bf2f(c2.s[e]);
        float xn = (xv - mu) * rsig * gam[cc] + bet[cc];
        float ge = 0.5f * xn * (1.f + erff(xn * 0.70710678118654752f));
        outp.s[e] = f2bf(ge);
    }
    int h = co >> 5, d = co & 31;
    if (proj == 0) {
        *(uint4*)(qb + ((((size_t)b * 8 + h) * 1024 + px) * 32 + d)) = outp.v;
    } else if (proj == 1) {
        *(uint4*)(kb2 + ((((size_t)b * 8 + h) * 1024 + px) * 32 + d)) = outp.v;
    } else {
        // Vx[bh][kca=px>>5][half=d>>4][lane=quad*16+(d&15)][j=px&7]
        ushort* vb = vx + ((size_t)b * 8 + h) * 32768;
        int kca = px >> 5, quad = (px >> 3) & 3, j = px & 7;
#pragma unroll
        for (int e = 0; e < 8; ++e) {
            int dd = d + e;
            vb[(((kca * 2 + (dd >> 4)) * 64) + quad * 16 + (dd & 15)) * 8 + j] = outp.s[e];
        }
    }
}

// ---------------------------------------------------------------------------
// Kernel 5: fused attention, KEY-SPLIT z=2 (2048 blocks -> ~8 blocks/CU).
//   Softmax via exp2(fma(S, log2e, bias')) — Bx pre-scaled. Writes
//   UNNORMALIZED bf16 O partials + fp32 l partials; combine_k finishes.
// ---------------------------------------------------------------------------
__global__ __launch_bounds__(256, 8) void attn_k(
    const ushort* __restrict__ qb, const ushort* __restrict__ kb,
    const ushort* __restrict__ vx, const ushort* __restrict__ Bx,
    ushort* __restrict__ Opart, float* __restrict__ lpart)
{
    __shared__ __align__(16) ushort Pl[4 * 16 * 72];
    int tid = threadIdx.x, wave = tid >> 6, lane = tid & 63;
    int quad = lane >> 4, c = lane & 15;
    int bh = blockIdx.y;               // b*8 + h
    int h = bh & 7;
    int z = blockIdx.z;
    int qbase = blockIdx.x * 64 + wave * 16;

    const ushort* Q  = qb + (size_t)bh * 1024 * 32;
    const ushort* Kp = kb + (size_t)bh * 1024 * 32;
    const ushort* Vb = vx + (size_t)bh * 32768;
    const ushort* bxp = Bx + (((size_t)(h * 64 + (qbase >> 4)) * 16) * 64 + lane) * 16;
    ushort* Pw = Pl + wave * 16 * 72;

    bf16x8 qf = *(const bf16x8*)&Q[(qbase + c) * 32 + quad * 8];

    float l_[4] = {0.f, 0.f, 0.f, 0.f};
    f32x4 Of0 = {0.f, 0.f, 0.f, 0.f}, Of1 = {0.f, 0.f, 0.f, 0.f};

    for (int kb64 = z * 512; kb64 < z * 512 + 512; kb64 += 64) {
        f32x4 S[4];
        f32x4 zf = {0.f, 0.f, 0.f, 0.f};
#pragma unroll
        for (int f = 0; f < 4; ++f) {
            bf16x8 kf = *(const bf16x8*)&Kp[(kb64 + f * 16 + c) * 32 + quad * 8];
            S[f] = __builtin_amdgcn_mfma_f32_16x16x32_bf16(qf, kf, zf, 0, 0, 0);
        }
        // fragment-ordered pre-scaled bias: 32 B per lane, coalesced
        union { uint4 v[2]; ushort s[16]; } bu;
        const uint4* bsrc = (const uint4*)(bxp + (size_t)(kb64 >> 6) * 1024);
        bu.v[0] = bsrc[0];
        bu.v[1] = bsrc[1];
#pragma unroll
        for (int f = 0; f < 4; ++f)
#pragma unroll
            for (int r = 0; r < 4; ++r) {
                float p = __builtin_amdgcn_exp2f(
                    fmaf(S[f][r], LOG2E, bf2f(bu.s[f * 4 + r])));
                S[f][r] = p;
                l_[r] += p;
            }
        // P (C-layout) -> LDS -> A-layout; per-wave slice, no barrier needed
#pragma unroll
        for (int f = 0; f < 4; ++f)
#pragma unroll
            for (int r = 0; r < 4; ++r)
                Pw[(quad * 4 + r) * 72 + f * 16 + c] = f2bf(S[f][r]);
#pragma unroll
        for (int kc = 0; kc < 2; ++kc) {
            int kca = (kb64 >> 5) + kc;
            bf16x8 pf = *(const bf16x8*)&Pw[c * 72 + kc * 32 + quad * 8];
            bf16x8 vf0 = *(const bf16x8*)&Vb[((kca * 2 + 0) * 64 + lane) * 8];
            Of0 = __builtin_amdgcn_mfma_f32_16x16x32_bf16(pf, vf0, Of0, 0, 0, 0);
            bf16x8 vf1 = *(const bf16x8*)&Vb[((kca * 2 + 1) * 64 + lane) * 8];
            Of1 = __builtin_amdgcn_mfma_f32_16x16x32_bf16(pf, vf1, Of1, 0, 0, 0);
        }
    }
#pragma unroll
    for (int r = 0; r < 4; ++r) {
        float l = l_[r];
        l += __shfl_xor(l, 1, 64);
        l += __shfl_xor(l, 2, 64);
        l += __shfl_xor(l, 4, 64);
        l += __shfl_xor(l, 8, 64);
        int qr = qbase + quad * 4 + r;
        size_t ob = (((size_t)z * 64 + bh) * 1024 + qr) * 32;
        Opart[ob + c]      = f2bf(Of0[r]);
        Opart[ob + 16 + c] = f2bf(Of1[r]);
        if (c == 0) lpart[(size_t)z * 65536 + bh * 1024 + qr] = l;
    }
}

// ---------------------------------------------------------------------------
// Kernel 6: combine key-split partials: attnout = (O0+O1)/(l0+l1), bf16,
//   written in [b][n][h*32+d] layout for the out-proj GEMM. (Separate
//   1024-block kernel — R11 showed fusing this into the 128-block out-proj
//   GEMM regresses: no latency-hiding capacity there.)
// ---------------------------------------------------------------------------
__global__ __launch_bounds__(256) void combine_k(const ushort* __restrict__ Opart,
                                                 const float* __restrict__ lpart,
                                                 ushort* __restrict__ attnout)
{
    int t = blockIdx.x * 256 + threadIdx.x;   // 262144 threads, 8 d each
    int g = t & 3;
    int qg = t >> 2;                          // bh*1024 + qr
    int bh = qg >> 10, qr = qg & 1023;
    int b = bh >> 3, h = bh & 7;
    size_t ob = ((size_t)qg) * 32 + g * 8;
    union { uint4 v; ushort s[8]; } o0, o1;
    o0.v = *(const uint4*)&Opart[ob];
    o1.v = *(const uint4*)&Opart[(size_t)64 * 1024 * 32 + ob];
    float inv = 1.f / (lpart[qg] + lpart[65536 + qg]);
    union { uint4 u; ushort s[8]; } o;
#pragma unroll
    for (int e = 0; e < 8; ++e)
        o.s[e] = f2bf((bf2f(o0.s[e]) + bf2f(o1.s[e])) * inv);
    *(uint4*)&attnout[(((size_t)b * 1024 + qr) * 256) + h * 32 + g * 8] = o.u;
}

// ---------------------------------------------------------------------------
extern "C" void kernel_launch(void* const* d_in, const int* in_sizes, int n_in,
                              void* d_out, int out_size, void* d_ws, size_t ws_size,
                              hipStream_t stream)
{
    const float* x    = (const float*)d_in[0];
    const float* wq   = (const float*)d_in[1];
    const float* wk   = (const float*)d_in[2];
    const float* wv   = (const float*)d_in[3];
    const float* gq   = (const float*)d_in[4];
    const float* bq   = (const float*)d_in[5];
    const float* gk   = (const float*)d_in[6];
    const float* bk   = (const float*)d_in[7];
    const float* gv   = (const float*)d_in[8];
    const float* bv   = (const float*)d_in[9];
    const float* btab = (const float*)d_in[10];
    const float* wo   = (const float*)d_in[11];
    const float* bo   = (const float*)d_in[12];
    float* out = (float*)d_out;

    char* w = (char*)d_ws;
    size_t off = 0;
    auto alloc = [&](size_t bytes) -> char* {
        char* p = w + off;
        off += (bytes + 255) & ~(size_t)255;
        return p;
    };
    ushort* Abuf    = (ushort*)alloc(8192ull * 2304 * 2);   // im2col patches (36.9 MB)
    ushort* Wbuf    = (ushort*)alloc(768ull * 2304 * 2);    // concat conv weights
    ushort* wo_bf   = (ushort*)alloc(65536ull * 2);         // out-proj weight
    ushort* Bx      = (ushort*)alloc(8192ull * 64 * 16 * 2);// bias frags (16.7 MB, DEDICATED)
    ushort* P0      = (ushort*)alloc(8192ull * 768 * 2);    // split-K partial 0 (bf16)
    ushort* P1      = (ushort*)alloc(8192ull * 768 * 2);    // split-K partial 1 (bf16)
    float2* part    = (float2*)alloc(48ull * 1024 * 8);     // stats partials
    float*  stats   = (float*)alloc(384);                   // [proj][b][sum,sumsq]
    ushort* Opart   = (ushort*)alloc(2ull * 64 * 1024 * 32 * 2);  // attn O partials (bf16)
    float*  lpart   = (float*)alloc(2ull * 64 * 1024 * 4);        // attn l partials
    // aliases into Abuf (dead after the conv GEMM; stream-ordered):
    ushort* qb      = (ushort*)Abuf;                        // 4 MB
    ushort* kb2     = qb  + 8ull * 8 * 1024 * 32;           // 4 MB
    ushort* vx      = kb2 + 8ull * 8 * 1024 * 32;           // 4 MB (fragment order)
    ushort* attnout = vx  + 8ull * 8 * 32 * 1024;           // 4 MB

    prep_k<<<3392, 256, 0, stream>>>(x, wq, wk, wv, wo, btab,
                                     Abuf, Wbuf, wo_bf, Bx);
    gemm_bt<<<dim3(64, 6, 2), 256, 0, stream>>>(Abuf, Wbuf, 8192, 768, 2304,
                                                P0, nullptr, nullptr, 0);
    stats1_k<<<3072, 256, 0, stream>>>(P0, P1, part);
    stats2_k<<<48, 256, 0, stream>>>(part, stats);
    gn_k<<<3072, 256, 0, stream>>>(P0, P1, stats, gq, bq, gk, bk, gv, bv,
                                   qb, kb2, vx);
    attn_k<<<dim3(16, 64, 2), 256, 0, stream>>>(qb, kb2, vx, Bx, Opart, lpart);
    combine_k<<<1024, 256, 0, stream>>>(Opart, lpart, attnout);
    gemm_bt<<<dim3(2, 64, 1), 256, 0, stream>>>(wo_bf, attnout, 256, 8192, 256,
                                                nullptr, out, bo, 1);
}